// Round 9
// baseline (341.474 us; speedup 1.0000x reference)
//
#include <hip/hip_runtime.h>
#include <hip/hip_bf16.h>

// Conv2dKan via implicit-GEMM MFMA (16x16x32 bf16). b=16, cin=cout=64, H=W=32, K=3, PAD=1, BASIS=8.
// out[b,o,pix] = bias[o] + sum_{i,k,s8} Wt[i,k,o,s]*Ah[b,i,pix+off(k),s]
//   Wt[...,0]=w, Wt[...,s]=w*c[s] (s=1..7), bf16   layout [i][kpos][o][s]
//   Ah = [silu(x), T1..T7(tanh x)] on 34x34 halo grid; border = act(0) = [0,0,-1,0,1,0,-1,0]
//   bias[o] = sum_{i,k} w*c[...,0]  (T0==1)
// Frag layouts (HW-verified R3/R5): 16x16x32 A/B: lane=(quad,l16), k=quad*8+s, m/n=l16;
//   C/D: col=l16, row=quad*4+r.
// R9: MEASUREMENT ROUND. R8 unchanged except kan_mfma body repeated 8x (idempotent
//   stores) so the dispatch exceeds the 45us fill and appears in rocprof top-5
//   with counters. Differential: big SQ_LDS_BANK_CONFLICT -> Wlds quad-stride
//   (4608B = bank 0) conflict; low busy + high FETCH -> af L3 latency; both low
//   + MfmaUtil low -> barrier/latency bound at 2 waves/SIMD.

#define CIN   64
#define COUT  64
#define HW    32
#define LL    1024
#define NS    8
#define AH    34
#define AHC   1156
#define REPEAT 8

typedef __attribute__((ext_vector_type(8))) short short8;
typedef __attribute__((ext_vector_type(4))) float f32x4;

// ws layout (bytes):
//   [0)       Wt   : 64*9*64*8 bf16 = 589824 B   ([i][kpos][o][s])
//   [589824)  bias : 64 f32         = 256 B
//   [590080)  Ah   : 16*64*1156*8 bf16 = 18939904 B

__global__ void prep_act_kernel(const float* __restrict__ x,
                                const float* __restrict__ w,
                                const float* __restrict__ c,
                                __hip_bfloat16* __restrict__ Wt,
                                float* __restrict__ bias,
                                __hip_bfloat16* __restrict__ Ah) {
    int bx = blockIdx.x;
    if (bx >= 4624) {
        bx -= 4624;
        if (bx >= 144) {
            // bias part: 64 parallel blocks, one o each; 64-lane wave reduce over i.
            const int o = bx - 144;
            const int i = threadIdx.x;       // lanes 0..63 participate
            if (i >= 64) return;
            float v = 0.f;
#pragma unroll
            for (int k = 0; k < 9; ++k) {
                const int idx = (i * COUT + o) * 9 + k;
                v += w[idx] * c[idx * 8];
            }
#pragma unroll
            for (int off = 32; off > 0; off >>= 1) v += __shfl_down(v, off);
            if (i == 0) bias[o] = v;
            return;
        }
        // Wt part: 144 blocks
        const int tid = bx * 256 + threadIdx.x;   // < 36864 = 64i*9k*64o
        const int i = tid / (9 * COUT);
        const int r = tid - i * 9 * COUT;
        const int k = r / COUT;
        const int o = r - k * COUT;
        const int widx = (i * COUT + o) * 9 + k;
        const float wv = w[widx];
        __hip_bfloat16* dst = Wt + (size_t)tid * NS;   // tid == (i*9+k)*64+o
        dst[0] = __float2bfloat16(wv);
#pragma unroll
        for (int s = 1; s < 8; ++s) dst[s] = __float2bfloat16(wv * c[widx * 8 + s]);
        return;
    }

    // act part: 4624 blocks, 1,183,744 threads = 16*64*1156 halo cells
    const int idx = bx * 256 + threadIdx.x;
    const int bi = idx / AHC;
    const int r  = idx - bi * AHC;
    const int yy = r / AH;
    const int xx = r - yy * AH;
    __align__(16) __hip_bfloat16 hv[8];
    if (yy >= 1 && yy <= 32 && xx >= 1 && xx <= 32) {
        float xv = x[bi * LL + (yy - 1) * HW + (xx - 1)];
        float e  = __expf(-xv);
        float res = xv / (1.f + e);              // silu
        float e2 = __expf(2.f * xv);
        float t  = 1.f - 2.f / (e2 + 1.f);       // tanh
        float T2 = 2.f * t * t  - 1.f;
        float T3 = 2.f * t * T2 - t;
        float T4 = 2.f * t * T3 - T2;
        float T5 = 2.f * t * T4 - T3;
        float T6 = 2.f * t * T5 - T4;
        float T7 = 2.f * t * T6 - T5;
        hv[0] = __float2bfloat16(res); hv[1] = __float2bfloat16(t);
        hv[2] = __float2bfloat16(T2);  hv[3] = __float2bfloat16(T3);
        hv[4] = __float2bfloat16(T4);  hv[5] = __float2bfloat16(T5);
        hv[6] = __float2bfloat16(T6);  hv[7] = __float2bfloat16(T7);
    } else {
        // activation of x=0: [0, 0, -1, 0, 1, 0, -1, 0]
        ((unsigned int*)hv)[0] = 0x00000000u;
        ((unsigned int*)hv)[1] = 0x0000BF80u;
        ((unsigned int*)hv)[2] = 0x00003F80u;
        ((unsigned int*)hv)[3] = 0x0000BF80u;
    }
    *(float4*)(Ah + (size_t)idx * NS) = *(const float4*)hv;
}

// grid (16 row-pairs, 16 batches, 2 o-halves), block 256 = 4 waves (khalf x pg-row).
// Wave: 32 pix (row y0+pg) x 32 o x K-half (32 ch as 8 chunks of 4ch).
__global__ __launch_bounds__(256) void kan_mfma_kernel(
        const __hip_bfloat16* __restrict__ Wt,
        const float* __restrict__ bias,
        const __hip_bfloat16* __restrict__ Ah,
        float* __restrict__ out) {
    // weights: [kh 2][il 4][k 9][o 32] float4(=8bf16) = 2304 float4 = 36864 B
    // epilogue overlay: float [2][64][33] = 16896 B
    __shared__ __align__(16) unsigned short Wlds[18432];

    const int tid   = threadIdx.x;
    const int wv    = tid >> 6;
    const int lane  = tid & 63;
    const int quad  = lane >> 4;      // channel within 4-ch chunk
    const int l16   = lane & 15;
    const int khalf = wv >> 1;        // K-half: channels [khalf*32, khalf*32+32)
    const int pg    = wv & 1;         // row within pair

    const int y0 = blockIdx.x * 2;
    const int b  = blockIdx.y;
    const int oh = blockIdx.z;        // o-half: [oh*32, oh*32+32)
    const int row = y0 + pg;

    const unsigned short* AhU = (const unsigned short*)Ah;
    const float4* wsrc = (const float4*)Wt;   // float4 idx = (i*9+k)*64 + o

    for (int rep = 0; rep < REPEAT; ++rep) {   // R9: repeat for rocprof visibility
    f32x4 acc[2][2];                  // [h pixel-group][nt]
#pragma unroll
    for (int h = 0; h < 2; ++h)
#pragma unroll
        for (int nt = 0; nt < 2; ++nt) acc[h][nt] = (f32x4){0.f, 0.f, 0.f, 0.f};

    for (int step = 0; step < 8; ++step) {
        __syncthreads();
        // stage 2304 float4 (both khalf chunks), 9 per thread
#pragma unroll
        for (int p = 0; p < 9; ++p) {
            const int j  = p * 256 + tid;
            const int kh = (j >= 1152);
            const int jj = j - (kh ? 1152 : 0);
            const int il = jj / 288;
            const int r2 = jj - il * 288;
            const int k  = r2 >> 5;
            const int oo = r2 & 31;
            ((float4*)Wlds)[j] =
                wsrc[(size_t)(((kh * 32 + step * 4 + il) * 9 + k) << 6) + (oh << 5) + oo];
        }
        __syncthreads();

        const int ch = khalf * 32 + step * 4 + quad;
        const unsigned short* ap = AhU +
            ((size_t)(b * CIN + ch) * AHC + (row + 1) * AH + 1) * NS;
        const unsigned short* wb = Wlds + khalf * 9216;   // 1152 float4 = 9216 ushorts
#pragma unroll
        for (int kpos = 0; kpos < 9; ++kpos) {
            const int dy = kpos / 3 - 1, dx = kpos % 3 - 1;
            short8 af0 = *(const short8*)(ap + (dy * AH + dx + l16) * NS);
            short8 af1 = *(const short8*)(ap + (dy * AH + dx + 16 + l16) * NS);
#pragma unroll
            for (int nt = 0; nt < 2; ++nt) {
                short8 wf = *(const short8*)(wb + ((quad * 9 + kpos) * 32 + nt * 16 + l16) * NS);
                acc[0][nt] = __builtin_amdgcn_mfma_f32_16x16x32_bf16(wf, af0, acc[0][nt], 0, 0, 0);
                acc[1][nt] = __builtin_amdgcn_mfma_f32_16x16x32_bf16(wf, af1, acc[1][nt], 0, 0, 0);
            }
        }
    }

    // reduce the two K-halves via LDS: red[khalf][pixl 64][ol 33 padded]
    __syncthreads();
    float* red = (float*)Wlds;
#pragma unroll
    for (int h = 0; h < 2; ++h)
#pragma unroll
        for (int nt = 0; nt < 2; ++nt)
#pragma unroll
            for (int r = 0; r < 4; ++r) {
                const int pixl = pg * 32 + h * 16 + l16;
                const int ol   = nt * 16 + quad * 4 + r;
                red[(khalf * 64 + pixl) * 33 + ol] = acc[h][nt][r];
            }
    __syncthreads();

#pragma unroll
    for (int rep2 = 0; rep2 < 8; ++rep2) {
        const int v = rep2 * 256 + tid;    // 2048 = 64 pix x 32 o
        const int pixl = v & 63;
        const int ol   = v >> 6;
        const int o    = (oh << 5) + ol;
        const float s  = red[pixl * 33 + ol] + red[(64 + pixl) * 33 + ol] + bias[o];
        out[(size_t)(b * COUT + o) * LL + (y0 + (pixl >> 5)) * HW + (pixl & 31)] = s;
    }
    }  // rep
}

extern "C" void kernel_launch(void* const* d_in, const int* in_sizes, int n_in,
                              void* d_out, int out_size, void* d_ws, size_t ws_size,
                              hipStream_t stream) {
    const float* x = (const float*)d_in[0];
    const float* w = (const float*)d_in[1];
    const float* c = (const float*)d_in[2];
    float* out = (float*)d_out;

    char* ws = (char*)d_ws;
    __hip_bfloat16* Wt   = (__hip_bfloat16*)(ws);
    float*          bias = (float*)(ws + 589824);
    __hip_bfloat16* Ah   = (__hip_bfloat16*)(ws + 590080);

    // 4624 act blocks + 144 Wt blocks + 64 bias blocks = 4832, all parallel
    prep_act_kernel<<<4832, 256, 0, stream>>>(x, w, c, Wt, bias, Ah);
    kan_mfma_kernel<<<dim3(16, 16, 2), 256, 0, stream>>>(Wt, bias, Ah, out);
}

// Round 10
// 90.246 us; speedup vs baseline: 3.7838x; 3.7838x over previous
//
#include <hip/hip_runtime.h>
#include <hip/hip_bf16.h>

// Conv2dKan via implicit-GEMM MFMA (16x16x32 bf16). b=16, cin=cout=64, H=W=32, K=3, PAD=1, BASIS=8.
// out[b,o,pix] = bias[o] + sum_{i,k,s8} Wt[i,k,o,s]*Ah[b,i,pix+off(k),s]
//   Wt[...,0]=w, Wt[...,s]=w*c[s] (s=1..7), bf16   layout [i][kpos][o][s]
//   Ah = [silu(x), T1..T7(tanh x)] on 34x34 halo grid; border = act(0) = [0,0,-1,0,1,0,-1,0]
//   bias[o] = sum_{i,k} w*c[...,0]  (T0==1)
// Frag layouts (HW-verified R3/R5): 16x16x32 A/B: lane=(quad,l16), k=quad*8+s, m/n=l16;
//   C/D: col=l16, row=quad*4+r.
// R10 (from R9 measurement: main=36us, MfmaUtil 11%, VALU 7.5%, FETCH=|Ah| per pass
//   -> latency-bound on 17-barrier serialized K-loop + af L3 misses):
//   1) weight staging via global_load_lds into DOUBLE-buffered LDS (73728B, 2 blk/CU),
//      one barrier per step (9 total), no VALU staging round-trip;
//   2) af registers software-pipelined (afb[2][18]): next step's loads issue before
//      current step's MFMAs;
//   3) XCD swizzle: grid.x = b  -> lin%8 = b%8 -> per-XCD Ah working set 2.4MB < L2.

#define CIN   64
#define COUT  64
#define HW    32
#define LL    1024
#define NS    8
#define AH    34
#define AHC   1156

typedef __attribute__((ext_vector_type(8))) short short8;
typedef __attribute__((ext_vector_type(4))) float f32x4;

typedef const __attribute__((address_space(1))) void gvoid_t;
typedef __attribute__((address_space(3))) void lvoid_t;

// ws layout (bytes):
//   [0)       Wt   : 64*9*64*8 bf16 = 589824 B   ([i][kpos][o][s])
//   [589824)  bias : 64 f32         = 256 B
//   [590080)  Ah   : 16*64*1156*8 bf16 = 18939904 B

__global__ void prep_act_kernel(const float* __restrict__ x,
                                const float* __restrict__ w,
                                const float* __restrict__ c,
                                __hip_bfloat16* __restrict__ Wt,
                                float* __restrict__ bias,
                                __hip_bfloat16* __restrict__ Ah) {
    int bx = blockIdx.x;
    if (bx >= 4624) {
        bx -= 4624;
        if (bx >= 144) {
            // bias part: 64 parallel blocks, one o each; 64-lane wave reduce over i.
            const int o = bx - 144;
            const int i = threadIdx.x;       // lanes 0..63 participate
            if (i >= 64) return;
            float v = 0.f;
#pragma unroll
            for (int k = 0; k < 9; ++k) {
                const int idx = (i * COUT + o) * 9 + k;
                v += w[idx] * c[idx * 8];
            }
#pragma unroll
            for (int off = 32; off > 0; off >>= 1) v += __shfl_down(v, off);
            if (i == 0) bias[o] = v;
            return;
        }
        // Wt part: 144 blocks
        const int tid = bx * 256 + threadIdx.x;   // < 36864 = 64i*9k*64o
        const int i = tid / (9 * COUT);
        const int r = tid - i * 9 * COUT;
        const int k = r / COUT;
        const int o = r - k * COUT;
        const int widx = (i * COUT + o) * 9 + k;
        const float wv = w[widx];
        __hip_bfloat16* dst = Wt + (size_t)tid * NS;   // tid == (i*9+k)*64+o
        dst[0] = __float2bfloat16(wv);
#pragma unroll
        for (int s = 1; s < 8; ++s) dst[s] = __float2bfloat16(wv * c[widx * 8 + s]);
        return;
    }

    // act part: 4624 blocks, 1,183,744 threads = 16*64*1156 halo cells
    const int idx = bx * 256 + threadIdx.x;
    const int bi = idx / AHC;
    const int r  = idx - bi * AHC;
    const int yy = r / AH;
    const int xx = r - yy * AH;
    __align__(16) __hip_bfloat16 hv[8];
    if (yy >= 1 && yy <= 32 && xx >= 1 && xx <= 32) {
        float xv = x[bi * LL + (yy - 1) * HW + (xx - 1)];
        float e  = __expf(-xv);
        float res = xv / (1.f + e);              // silu
        float e2 = __expf(2.f * xv);
        float t  = 1.f - 2.f / (e2 + 1.f);       // tanh
        float T2 = 2.f * t * t  - 1.f;
        float T3 = 2.f * t * T2 - t;
        float T4 = 2.f * t * T3 - T2;
        float T5 = 2.f * t * T4 - T3;
        float T6 = 2.f * t * T5 - T4;
        float T7 = 2.f * t * T6 - T5;
        hv[0] = __float2bfloat16(res); hv[1] = __float2bfloat16(t);
        hv[2] = __float2bfloat16(T2);  hv[3] = __float2bfloat16(T3);
        hv[4] = __float2bfloat16(T4);  hv[5] = __float2bfloat16(T5);
        hv[6] = __float2bfloat16(T6);  hv[7] = __float2bfloat16(T7);
    } else {
        // activation of x=0: [0, 0, -1, 0, 1, 0, -1, 0]
        ((unsigned int*)hv)[0] = 0x00000000u;
        ((unsigned int*)hv)[1] = 0x0000BF80u;
        ((unsigned int*)hv)[2] = 0x00003F80u;
        ((unsigned int*)hv)[3] = 0x0000BF80u;
    }
    *(float4*)(Ah + (size_t)idx * NS) = *(const float4*)hv;
}

// grid (16 b, 16 row-pairs, 2 o-halves) -- x=b for XCD L2 locality.
// block 256 = 4 waves (khalf x pg-row). Wave: 32 pix x 32 o x K-half.
__global__ __launch_bounds__(256, 2) void kan_mfma_kernel(
        const __hip_bfloat16* __restrict__ Wt,
        const float* __restrict__ bias,
        const __hip_bfloat16* __restrict__ Ah,
        float* __restrict__ out) {
    // double-buffered weights: 2 x [kh 2][il 4][k 9][o 32] float4 = 2 x 36864 B
    // epilogue overlay: float [2][64][33] = 16896 B
    __shared__ __align__(16) unsigned short Wlds[36864];

    const int tid   = threadIdx.x;
    const int wv    = tid >> 6;
    const int lane  = tid & 63;
    const int quad  = lane >> 4;      // channel within 4-ch chunk
    const int l16   = lane & 15;
    const int khalf = wv >> 1;        // K-half: channels [khalf*32, khalf*32+32)
    const int pg    = wv & 1;         // row within pair

    const int b  = blockIdx.x;        // XCD swizzle: lin%8 == b%8
    const int y0 = blockIdx.y * 2;
    const int oh = blockIdx.z;        // o-half: [oh*32, oh*32+32)
    const int row = y0 + pg;

    const unsigned short* AhU = (const unsigned short*)Ah;
    const float4* wsrc = (const float4*)Wt;   // float4 idx = (i*9+k)*64 + o

    // af lane base for (khalf, quad); step advance = 4*AHC*NS ushorts
    const unsigned short* apb = AhU +
        ((size_t)(b * CIN + khalf * 32 + quad) * AHC + (row + 1) * AH + 1) * NS;

    f32x4 acc[2][2];                  // [h pixel-group][nt]
#pragma unroll
    for (int h = 0; h < 2; ++h)
#pragma unroll
        for (int nt = 0; nt < 2; ++nt) acc[h][nt] = (f32x4){0.f, 0.f, 0.f, 0.f};

    short8 afb[2][18];                // software-pipelined activation fragments

    // ---- staging DMA: 2304 float4 per step, 9 per thread, dst = base + lane*16 ----
    auto stage_dma = [&](int step, int bufsel) {
        float4* dstb = (float4*)Wlds + bufsel * 1152 * 2;   // 2304 float4 per buffer
#pragma unroll
        for (int p = 0; p < 9; ++p) {
            const int j  = p * 256 + tid;
            const int kh = (j >= 1152);
            const int jj = j - (kh ? 1152 : 0);
            const int il = jj / 288;
            const int r2 = jj - il * 288;
            const int k  = r2 >> 5;
            const int oo = r2 & 31;
            const float4* src =
                wsrc + (size_t)(((kh * 32 + step * 4 + il) * 9 + k) << 6) + (oh << 5) + oo;
            __builtin_amdgcn_global_load_lds((gvoid_t*)src, (lvoid_t*)(dstb + j), 16, 0, 0);
        }
    };
    auto af_load = [&](int step, short8* dst) {
        const unsigned short* ap = apb + (size_t)step * 4 * AHC * NS;
#pragma unroll
        for (int kpos = 0; kpos < 9; ++kpos) {
            const int dy = kpos / 3 - 1, dx = kpos % 3 - 1;
            dst[kpos * 2 + 0] = *(const short8*)(ap + (dy * AH + dx + l16) * NS);
            dst[kpos * 2 + 1] = *(const short8*)(ap + (dy * AH + dx + 16 + l16) * NS);
        }
    };

    // prologue: DMA step 0 into buf0, prefetch af step 0
    stage_dma(0, 0);
    af_load(0, afb[0]);
    __syncthreads();   // drains the DMA (vmcnt) and aligns waves

#pragma unroll
    for (int step = 0; step < 8; ++step) {
        if (step < 7) {
            stage_dma(step + 1, (step + 1) & 1);    // DMA next weights (other buffer)
            af_load(step + 1, afb[(step + 1) & 1]); // prefetch next activations
        }
        const unsigned short* wb = Wlds + (step & 1) * 18432 + khalf * 9216;
        const short8* cur = afb[step & 1];
#pragma unroll
        for (int kpos = 0; kpos < 9; ++kpos) {
#pragma unroll
            for (int nt = 0; nt < 2; ++nt) {
                short8 wf = *(const short8*)(wb + ((quad * 9 + kpos) * 32 + nt * 16 + l16) * NS);
                acc[0][nt] = __builtin_amdgcn_mfma_f32_16x16x32_bf16(wf, cur[kpos * 2 + 0], acc[0][nt], 0, 0, 0);
                acc[1][nt] = __builtin_amdgcn_mfma_f32_16x16x32_bf16(wf, cur[kpos * 2 + 1], acc[1][nt], 0, 0, 0);
            }
        }
        __syncthreads();   // drains next-step DMA; separates buffer reuse
    }

    // reduce the two K-halves via LDS: red[khalf][pixl 64][ol 33 padded]
    float* red = (float*)Wlds;
#pragma unroll
    for (int h = 0; h < 2; ++h)
#pragma unroll
        for (int nt = 0; nt < 2; ++nt)
#pragma unroll
            for (int r = 0; r < 4; ++r) {
                const int pixl = pg * 32 + h * 16 + l16;
                const int ol   = nt * 16 + quad * 4 + r;
                red[(khalf * 64 + pixl) * 33 + ol] = acc[h][nt][r];
            }
    __syncthreads();

#pragma unroll
    for (int rep2 = 0; rep2 < 8; ++rep2) {
        const int v = rep2 * 256 + tid;    // 2048 = 64 pix x 32 o
        const int pixl = v & 63;
        const int ol   = v >> 6;
        const int o    = (oh << 5) + ol;
        const float s  = red[pixl * 33 + ol] + red[(64 + pixl) * 33 + ol] + bias[o];
        out[(size_t)(b * COUT + o) * LL + (y0 + (pixl >> 5)) * HW + (pixl & 31)] = s;
    }
}

extern "C" void kernel_launch(void* const* d_in, const int* in_sizes, int n_in,
                              void* d_out, int out_size, void* d_ws, size_t ws_size,
                              hipStream_t stream) {
    const float* x = (const float*)d_in[0];
    const float* w = (const float*)d_in[1];
    const float* c = (const float*)d_in[2];
    float* out = (float*)d_out;

    char* ws = (char*)d_ws;
    __hip_bfloat16* Wt   = (__hip_bfloat16*)(ws);
    float*          bias = (float*)(ws + 589824);
    __hip_bfloat16* Ah   = (__hip_bfloat16*)(ws + 590080);

    // 4624 act blocks + 144 Wt blocks + 64 bias blocks = 4832, all parallel
    prep_act_kernel<<<4832, 256, 0, stream>>>(x, w, c, Wt, bias, Ah);
    kan_mfma_kernel<<<dim3(16, 16, 2), 256, 0, stream>>>(Wt, bias, Ah, out);
}

// Round 11
// 89.655 us; speedup vs baseline: 3.8087x; 1.0066x over previous
//
#include <hip/hip_runtime.h>
#include <hip/hip_bf16.h>

// Conv2dKan, fully fused MFMA kernel. b=16, cin=cout=64, H=W=32, K=3, PAD=1, BASIS=8.
// out[b,o,pix] = bias[o] + sum_{i,k,s8} Wt[i,k,o,s]*act(x[b,i,pix+off(k)])[s]
//   Wt[...,0]=w, Wt[...,s]=w*c[s] (s=1..7) bf16, layout [i][kpos][o][s]
//   act(x) = [silu(x), T1..T7(tanh x)] bf16; act(pad) = act(0) = [0,0,-1,0,1,0,-1,0]
//   bias[o] = sum_{i,k} w*c[...,0]  (T0==1)
// MFMA 16x16x32 bf16 (layouts HW-verified R3/R5): A/B: lane=(quad,l16), k=quad*8+s;
//   C/D: col=l16, row=quad*4+r.
// R11 (from R9/R10: main ~35us latency-bound on af HBM misses — warm FETCH = |Ah|
//   every pass; pipelining/swizzle neutral): ELIMINATE Ah. Each wave recomputes its
//   step's activations (4ch x 3rows x 34cols) into PRIVATE LDS scratch (no barrier),
//   MFMAs read af from LDS. Steady-state global = x (0.5MB/XCD, L2-resident) +
//   Wt (0.6MB, L2-resident) -> no HBM in the hot loop. LDS = 36864B weights
//   (single-buffer global_load_lds DMA; drain overlapped by act VALU) + 4x6528B
//   scratch = 62976B -> 2 blocks/CU. Grid (b,rp,oh): lin%8=b%8 XCD swizzle.

#define CIN   64
#define COUT  64
#define HW    32
#define LL    1024
#define NS    8

typedef __attribute__((ext_vector_type(8))) short short8;
typedef __attribute__((ext_vector_type(4))) float f32x4;

typedef const __attribute__((address_space(1))) void gvoid_t;
typedef __attribute__((address_space(3))) void lvoid_t;

// ws layout (bytes):
//   [0)       Wt   : 64*9*64*8 bf16 = 589824 B   ([i][kpos][o][s])
//   [589824)  bias : 64 f32         = 256 B

__global__ void prep_kernel(const float* __restrict__ w,
                            const float* __restrict__ c,
                            __hip_bfloat16* __restrict__ Wt,
                            float* __restrict__ bias) {
    int bx = blockIdx.x;
    if (bx >= 144) {
        // bias part: 64 parallel blocks, one o each; 64-lane wave reduce over i.
        const int o = bx - 144;
        const int i = threadIdx.x;
        if (i >= 64) return;
        float v = 0.f;
#pragma unroll
        for (int k = 0; k < 9; ++k) {
            const int idx = (i * COUT + o) * 9 + k;
            v += w[idx] * c[idx * 8];
        }
#pragma unroll
        for (int off = 32; off > 0; off >>= 1) v += __shfl_down(v, off);
        if (i == 0) bias[o] = v;
        return;
    }
    // Wt part: 144 blocks
    const int tid = bx * 256 + threadIdx.x;   // < 36864 = 64i*9k*64o
    const int i = tid / (9 * COUT);
    const int r = tid - i * 9 * COUT;
    const int k = r / COUT;
    const int o = r - k * COUT;
    const int widx = (i * COUT + o) * 9 + k;
    const float wv = w[widx];
    __hip_bfloat16* dst = Wt + (size_t)tid * NS;   // tid == (i*9+k)*64+o
    dst[0] = __float2bfloat16(wv);
#pragma unroll
    for (int s = 1; s < 8; ++s) dst[s] = __float2bfloat16(wv * c[widx * 8 + s]);
}

// grid (16 b, 16 row-pairs, 2 o-halves) -- x=b so lin%8=b%8 (XCD L2 locality on x).
// block 256 = 4 waves (khalf x pg-row). Wave: 32 pix (row y0+pg) x 32 o x K-half.
__global__ __launch_bounds__(256, 2) void kan_fused_kernel(
        const float* __restrict__ x,
        const __hip_bfloat16* __restrict__ Wt,
        const float* __restrict__ bias,
        float* __restrict__ out) {
    // [0, 18432) ushorts: weight buffer [kh2][il4][k9][o32] float4 = 36864 B
    //   (epilogue overlay: float red[2][64][33] = 16896 B)
    // [18432, 31488): 4 x 3264 ushorts per-wave act scratch [ch4][row3][col34] x 16B
    __shared__ __align__(16) unsigned short Wlds[31488];

    const int tid   = threadIdx.x;
    const int wv    = tid >> 6;
    const int lane  = tid & 63;
    const int quad  = lane >> 4;      // channel within 4-ch chunk
    const int l16   = lane & 15;
    const int khalf = wv >> 1;        // K-half: channels [khalf*32, khalf*32+32)
    const int pg    = wv & 1;         // row within pair

    const int b  = blockIdx.x;
    const int y0 = blockIdx.y * 2;
    const int oh = blockIdx.z;        // o-half: [oh*32, oh*32+32)
    const int row = y0 + pg;

    const float4* wsrc = (const float4*)Wt;   // float4 idx = (i*9+k)*64 + o
    unsigned short* scratch = Wlds + 18432 + wv * 3264;   // 408 cells x 8 ushorts

    f32x4 acc[2][2];                  // [h pixel-group][nt]
#pragma unroll
    for (int h = 0; h < 2; ++h)
#pragma unroll
        for (int nt = 0; nt < 2; ++nt) acc[h][nt] = (f32x4){0.f, 0.f, 0.f, 0.f};

    for (int step = 0; step < 8; ++step) {
        __syncthreads();   // previous step's MFMA reads of weight buffer are done
        // ---- DMA this step's weights: 2304 float4, 9 per thread ----
#pragma unroll
        for (int p = 0; p < 9; ++p) {
            const int j  = p * 256 + tid;
            const int kh = (j >= 1152);
            const int jj = j - (kh ? 1152 : 0);
            const int il = jj / 288;
            const int r2 = jj - il * 288;
            const int k  = r2 >> 5;
            const int oo = r2 & 31;
            const float4* src =
                wsrc + (size_t)(((kh * 32 + step * 4 + il) * 9 + k) << 6) + (oh << 5) + oo;
            __builtin_amdgcn_global_load_lds((gvoid_t*)src, (lvoid_t*)((float4*)Wlds + j), 16, 0, 0);
        }
        // ---- recompute this step's activations into private scratch (408 cells):
        //      overlaps the DMA drain; no barrier needed (per-wave scratch) ----
        const int chbase = khalf * 32 + step * 4;
#pragma unroll
        for (int p = 0; p < 7; ++p) {
            const int cell = p * 64 + lane;
            if (cell < 408) {
                const int ch  = cell / 102;
                const int rem = cell - ch * 102;
                const int r3  = rem / 34;
                const int col = rem - r3 * 34;
                const int gy  = row - 1 + r3;
                const int gx  = col - 1;
                __align__(16) unsigned int u[4];
                if ((unsigned)gy < 32u && (unsigned)gx < 32u) {
                    const float xv = x[((size_t)(b * CIN + chbase + ch) * HW + gy) * HW + gx];
                    const float e   = __expf(-xv);
                    const float res = xv / (1.f + e);          // silu
                    const float e2  = __expf(2.f * xv);
                    const float t   = 1.f - 2.f / (e2 + 1.f);  // tanh
                    const float T2 = 2.f * t * t  - 1.f;
                    const float T3 = 2.f * t * T2 - t;
                    const float T4 = 2.f * t * T3 - T2;
                    const float T5 = 2.f * t * T4 - T3;
                    const float T6 = 2.f * t * T5 - T4;
                    const float T7 = 2.f * t * T6 - T5;
                    __hip_bfloat16* hv = (__hip_bfloat16*)u;
                    hv[0] = __float2bfloat16(res); hv[1] = __float2bfloat16(t);
                    hv[2] = __float2bfloat16(T2);  hv[3] = __float2bfloat16(T3);
                    hv[4] = __float2bfloat16(T4);  hv[5] = __float2bfloat16(T5);
                    hv[6] = __float2bfloat16(T6);  hv[7] = __float2bfloat16(T7);
                } else {
                    // act(0): [0, 0, -1, 0, 1, 0, -1, 0]
                    u[0] = 0x00000000u; u[1] = 0x0000BF80u;
                    u[2] = 0x00003F80u; u[3] = 0x0000BF80u;
                }
                *(float4*)(scratch + cell * 8) = *(const float4*)u;
            }
        }
        __syncthreads();   // drains DMA (vmcnt0 before barrier); weights ready

        // ---- MFMA on LDS weights + private-scratch activations ----
        const unsigned short* wb = Wlds + khalf * 9216;
#pragma unroll
        for (int kpos = 0; kpos < 9; ++kpos) {
            const int dy = kpos / 3 - 1, dx = kpos % 3 - 1;
            const int cb = quad * 102 + (dy + 1) * 34 + (dx + 1);
            short8 af0 = *(const short8*)(scratch + (cb + l16) * 8);
            short8 af1 = *(const short8*)(scratch + (cb + 16 + l16) * 8);
#pragma unroll
            for (int nt = 0; nt < 2; ++nt) {
                short8 wf = *(const short8*)(wb + ((quad * 9 + kpos) * 32 + nt * 16 + l16) * NS);
                acc[0][nt] = __builtin_amdgcn_mfma_f32_16x16x32_bf16(wf, af0, acc[0][nt], 0, 0, 0);
                acc[1][nt] = __builtin_amdgcn_mfma_f32_16x16x32_bf16(wf, af1, acc[1][nt], 0, 0, 0);
            }
        }
    }

    // reduce the two K-halves via LDS: red[khalf][pixl 64][ol 33 padded]
    __syncthreads();   // all waves done reading weight buffer before overlay
    float* red = (float*)Wlds;
#pragma unroll
    for (int h = 0; h < 2; ++h)
#pragma unroll
        for (int nt = 0; nt < 2; ++nt)
#pragma unroll
            for (int r = 0; r < 4; ++r) {
                const int pixl = pg * 32 + h * 16 + l16;
                const int ol   = nt * 16 + quad * 4 + r;
                red[(khalf * 64 + pixl) * 33 + ol] = acc[h][nt][r];
            }
    __syncthreads();

#pragma unroll
    for (int rep2 = 0; rep2 < 8; ++rep2) {
        const int v = rep2 * 256 + tid;    // 2048 = 64 pix x 32 o
        const int pixl = v & 63;
        const int ol   = v >> 6;
        const int o    = (oh << 5) + ol;
        const float s  = red[pixl * 33 + ol] + red[(64 + pixl) * 33 + ol] + bias[o];
        out[(size_t)(b * COUT + o) * LL + (y0 + (pixl >> 5)) * HW + (pixl & 31)] = s;
    }
}

extern "C" void kernel_launch(void* const* d_in, const int* in_sizes, int n_in,
                              void* d_out, int out_size, void* d_ws, size_t ws_size,
                              hipStream_t stream) {
    const float* x = (const float*)d_in[0];
    const float* w = (const float*)d_in[1];
    const float* c = (const float*)d_in[2];
    float* out = (float*)d_out;

    char* ws = (char*)d_ws;
    __hip_bfloat16* Wt   = (__hip_bfloat16*)(ws);
    float*          bias = (float*)(ws + 589824);

    prep_kernel<<<208, 256, 0, stream>>>(w, c, Wt, bias);
    kan_fused_kernel<<<dim3(16, 16, 2), 256, 0, stream>>>(x, Wt, bias, out);
}

// Round 12
// 85.813 us; speedup vs baseline: 3.9793x; 1.0448x over previous
//
#include <hip/hip_runtime.h>
#include <hip/hip_bf16.h>

// Conv2dKan, fused barrier-free MFMA kernel. b=16, cin=cout=64, H=W=32, K=3, PAD=1, BASIS=8.
// out[b,o,pix] = bias[o] + sum_{i,k,s8} Wt[i,k,o,s]*act(x[b,i,pix+off(k)])[s]
//   Wt[...,0]=w, Wt[...,s]=w*c[s] (s=1..7) bf16, layout [i][kpos][o][s]
//   act(x) = [silu(x), T1..T7(tanh x)] bf16; act(pad) = act(0) = [0,0,-1,0,1,0,-1,0]
//   bias[o] = sum_{i,k} w*c[...,0]  (T0==1)
// MFMA 16x16x32 bf16 (layouts HW-verified R3/R5): A/B: lane=(quad,l16), k=quad*8+s;
//   C/D: col=l16, row=quad*4+r.
// R12 (from R9-R11: main ~35us is STALL-bound at 2 waves/SIMD — MfmaUtil 11%,
//   VALUBusy 7.5%, no BW ceiling; staging/pipelining/Ah-elimination all neutral):
//   raise TLP and delete K-loop barriers.
//   - wf fragments read DIRECTLY from global (Wt 590KB = L2-resident; coalesced
//     256B segments) -> no weight LDS, no DMA, no __syncthreads in the K-loop.
//   - K split 4-way IN-BLOCK: wave = kquarter (16ch), one row, 32pix x 32o.
//     grid (16b, 32rows, 2oh) = 1024 blocks x 4 waves = 4096 waves = 4/SIMD,
//     4 blocks/CU (LDS = 4x6528B private act scratch = 26112B).
//   - epilogue: single barrier pair, padded LDS reduce over 4 kq, coalesced stores.

#define CIN   64
#define COUT  64
#define HW    32
#define LL    1024
#define NS    8

typedef __attribute__((ext_vector_type(8))) short short8;
typedef __attribute__((ext_vector_type(4))) float f32x4;

// ws layout (bytes):
//   [0)       Wt   : 64*9*64*8 bf16 = 589824 B   ([i][kpos][o][s])
//   [589824)  bias : 64 f32         = 256 B

__global__ void prep_kernel(const float* __restrict__ w,
                            const float* __restrict__ c,
                            __hip_bfloat16* __restrict__ Wt,
                            float* __restrict__ bias) {
    int bx = blockIdx.x;
    if (bx >= 144) {
        // bias part: 64 parallel blocks, one o each; 64-lane wave reduce over i.
        const int o = bx - 144;
        const int i = threadIdx.x;
        if (i >= 64) return;
        float v = 0.f;
#pragma unroll
        for (int k = 0; k < 9; ++k) {
            const int idx = (i * COUT + o) * 9 + k;
            v += w[idx] * c[idx * 8];
        }
#pragma unroll
        for (int off = 32; off > 0; off >>= 1) v += __shfl_down(v, off);
        if (i == 0) bias[o] = v;
        return;
    }
    // Wt part: 144 blocks
    const int tid = bx * 256 + threadIdx.x;   // < 36864 = 64i*9k*64o
    const int i = tid / (9 * COUT);
    const int r = tid - i * 9 * COUT;
    const int k = r / COUT;
    const int o = r - k * COUT;
    const int widx = (i * COUT + o) * 9 + k;
    const float wv = w[widx];
    __hip_bfloat16* dst = Wt + (size_t)tid * NS;   // tid == (i*9+k)*64+o
    dst[0] = __float2bfloat16(wv);
#pragma unroll
    for (int s = 1; s < 8; ++s) dst[s] = __float2bfloat16(wv * c[widx * 8 + s]);
}

// grid (16 b, 32 rows, 2 o-halves) -- x=b so lin%8=b%8 (XCD L2 locality).
// block 256 = 4 INDEPENDENT waves = 4 K-quarters. Wave: 32pix(row) x 32o x 16ch.
__global__ __launch_bounds__(256, 4) void kan_fused_kernel(
        const float* __restrict__ x,
        const __hip_bfloat16* __restrict__ Wt,
        const float* __restrict__ bias,
        float* __restrict__ out) {
    // 4 x 3264 ushorts per-wave act scratch [ch4][row3][col34] x 16B = 26112 B
    // epilogue overlay: float red[kq4][pix32][o 33pad] = 16896 B
    __shared__ __align__(16) unsigned short Wlds[13056];

    const int tid   = threadIdx.x;
    const int wv    = tid >> 6;       // = kq (K-quarter)
    const int lane  = tid & 63;
    const int quad  = lane >> 4;      // channel within 4-ch chunk
    const int l16   = lane & 15;

    const int b   = blockIdx.x;
    const int row = blockIdx.y;
    const int oh  = blockIdx.z;       // o-half: [oh*32, oh*32+32)

    const unsigned short* WtU = (const unsigned short*)Wt;
    unsigned short* scratch = Wlds + wv * 3264;   // 408 cells x 8 ushorts

    f32x4 acc[2][2];                  // [h pixel-group][nt]
#pragma unroll
    for (int h = 0; h < 2; ++h)
#pragma unroll
        for (int nt = 0; nt < 2; ++nt) acc[h][nt] = (f32x4){0.f, 0.f, 0.f, 0.f};

    for (int chunk = 0; chunk < 4; ++chunk) {
        const int chbase = wv * 16 + chunk * 4;
        // ---- recompute this chunk's activations into private scratch (408 cells).
        //      No barrier: scratch is per-wave; lgkmcnt waits are automatic. ----
#pragma unroll
        for (int p = 0; p < 7; ++p) {
            const int cell = p * 64 + lane;
            if (cell < 408) {
                const int ch  = cell / 102;
                const int rem = cell - ch * 102;
                const int r3  = rem / 34;
                const int col = rem - r3 * 34;
                const int gy  = row - 1 + r3;
                const int gx  = col - 1;
                __align__(16) unsigned int u[4];
                if ((unsigned)gy < 32u && (unsigned)gx < 32u) {
                    const float xv = x[((size_t)(b * CIN + chbase + ch) * HW + gy) * HW + gx];
                    const float e   = __expf(-xv);
                    const float res = xv / (1.f + e);          // silu
                    const float e2  = __expf(2.f * xv);
                    const float t   = 1.f - 2.f / (e2 + 1.f);  // tanh
                    const float T2 = 2.f * t * t  - 1.f;
                    const float T3 = 2.f * t * T2 - t;
                    const float T4 = 2.f * t * T3 - T2;
                    const float T5 = 2.f * t * T4 - T3;
                    const float T6 = 2.f * t * T5 - T4;
                    const float T7 = 2.f * t * T6 - T5;
                    __hip_bfloat16* hv = (__hip_bfloat16*)u;
                    hv[0] = __float2bfloat16(res); hv[1] = __float2bfloat16(t);
                    hv[2] = __float2bfloat16(T2);  hv[3] = __float2bfloat16(T3);
                    hv[4] = __float2bfloat16(T4);  hv[5] = __float2bfloat16(T5);
                    hv[6] = __float2bfloat16(T6);  hv[7] = __float2bfloat16(T7);
                } else {
                    // act(0): [0, 0, -1, 0, 1, 0, -1, 0]
                    u[0] = 0x00000000u; u[1] = 0x0000BF80u;
                    u[2] = 0x00003F80u; u[3] = 0x0000BF80u;
                }
                *(float4*)(scratch + cell * 8) = *(const float4*)u;
            }
        }

        // ---- MFMA: af from private scratch, wf straight from global (L2) ----
        const unsigned short* wchunk = WtU +
            ((size_t)(chbase + quad) * 9 * COUT + (oh << 5) + l16) * NS;
#pragma unroll
        for (int kpos = 0; kpos < 9; ++kpos) {
            const int dy = kpos / 3 - 1, dx = kpos % 3 - 1;
            const int cb = quad * 102 + (dy + 1) * 34 + (dx + 1);
            short8 af0 = *(const short8*)(scratch + (cb + l16) * 8);
            short8 af1 = *(const short8*)(scratch + (cb + 16 + l16) * 8);
#pragma unroll
            for (int nt = 0; nt < 2; ++nt) {
                short8 wf = *(const short8*)(wchunk + (kpos * COUT + nt * 16) * NS);
                acc[0][nt] = __builtin_amdgcn_mfma_f32_16x16x32_bf16(wf, af0, acc[0][nt], 0, 0, 0);
                acc[1][nt] = __builtin_amdgcn_mfma_f32_16x16x32_bf16(wf, af1, acc[1][nt], 0, 0, 0);
            }
        }
    }

    // ---- epilogue: reduce 4 K-quarters via padded LDS, single barrier pair ----
    __syncthreads();   // all waves done with private scratch before overlay
    float* red = (float*)Wlds;       // red[kq][pix32][33]
#pragma unroll
    for (int h = 0; h < 2; ++h)
#pragma unroll
        for (int nt = 0; nt < 2; ++nt)
#pragma unroll
            for (int r = 0; r < 4; ++r) {
                const int p  = h * 16 + l16;
                const int ol = nt * 16 + quad * 4 + r;
                red[(wv * 32 + p) * 33 + ol] = acc[h][nt][r];
            }
    __syncthreads();

#pragma unroll
    for (int rep = 0; rep < 4; ++rep) {
        const int v  = rep * 256 + tid;   // 1024 = 32 pix x 32 o
        const int p  = v & 31;
        const int ol = v >> 5;
        const int o  = (oh << 5) + ol;
        const float s = red[p * 33 + ol] + red[(32 + p) * 33 + ol]
                      + red[(64 + p) * 33 + ol] + red[(96 + p) * 33 + ol] + bias[o];
        out[(size_t)(b * COUT + o) * LL + row * HW + p] = s;
    }
}

extern "C" void kernel_launch(void* const* d_in, const int* in_sizes, int n_in,
                              void* d_out, int out_size, void* d_ws, size_t ws_size,
                              hipStream_t stream) {
    const float* x = (const float*)d_in[0];
    const float* w = (const float*)d_in[1];
    const float* c = (const float*)d_in[2];
    float* out = (float*)d_out;

    char* ws = (char*)d_ws;
    __hip_bfloat16* Wt   = (__hip_bfloat16*)(ws);
    float*          bias = (float*)(ws + 589824);

    prep_kernel<<<208, 256, 0, stream>>>(w, c, Wt, bias);
    kan_fused_kernel<<<dim3(16, 32, 2), 256, 0, stream>>>(x, Wt, bias, out);
}